// Round 13
// baseline (413.251 us; speedup 1.0000x reference)
//
#include <hip/hip_runtime.h>
#include <math.h>

#define COUT 192
#define NF 12
#define TSC 36.06737602222409f     // tanh(12.5 d) = 1 - 2/(exp2(TSC*d)+1)

typedef __bf16 bf16_8 __attribute__((ext_vector_type(8)));
typedef float  f32x4  __attribute__((ext_vector_type(4)));

__device__ __forceinline__ float fast_tanh_f(float v, float cenc) {
    float e = __builtin_amdgcn_exp2f(__builtin_fmaf(v, TSC, -cenc));
    return 1.0f - 2.0f * __builtin_amdgcn_rcpf(e + 1.0f);
}

// ---- merged weight prep + x00p zero-fill.
// Bp[(cc*NF+nf)*64 + lane][8] bf16; cc=c*2+t, k=(lane>>4)*8+e, n=nf*16+(lane&15);
// t=0 -> m_w, t=1 -> -2*w_w; k>=25 zero-pad.
__global__ void prep_all(const float* __restrict__ m1_w, const float* __restrict__ w1_w,
                         const float* __restrict__ m2_w, const float* __restrict__ w2_w,
                         const float* __restrict__ m3_w, const float* __restrict__ w3_w,
                         __bf16* __restrict__ Bp1, __bf16* __restrict__ Bp2,
                         __bf16* __restrict__ Bp3, float* __restrict__ x00p) {
    int idx = blockIdx.x * 256 + threadIdx.x;
    const int N1 = 3 * 2 * NF * 64, N2 = 192 * 2 * NF * 64;
    const int NW = N1 + 2 * N2;
    if (idx >= NW) {
        int zi = idx - NW;                       // zero x00p: 12288*400 floats as float4
        if (zi < 1228800) ((f32x4*)x00p)[zi] = (f32x4){0.f, 0.f, 0.f, 0.f};
        return;
    }
    const float *mw, *ww; __bf16* Bp; int CIN, li;
    if (idx < N1)           { mw = m1_w; ww = w1_w; Bp = Bp1; CIN = 3;   li = idx; }
    else if (idx < N1 + N2) { mw = m2_w; ww = w2_w; Bp = Bp2; CIN = 192; li = idx - N1; }
    else                    { mw = m3_w; ww = w3_w; Bp = Bp3; CIN = 192; li = idx - N1 - N2; }
    int lane = li & 63;
    int nf = (li >> 6) % NF;
    int cc = li / (NF * 64);
    int t = cc & 1, c = cc >> 1;
    int n = nf * 16 + (lane & 15);
    int k0 = (lane >> 4) * 8;
    bf16_8 v;
    #pragma unroll
    for (int e = 0; e < 8; ++e) {
        int k = k0 + e;
        float val = 0.f;
        if (k < 25) {
            val = (t == 0) ? mw[((size_t)n * CIN + c) * 25 + k]
                           : -2.0f * ww[((size_t)n * CIN + c) * 25 + k];
        }
        v[e] = (__bf16)val;
    }
    *(bf16_8*)(Bp + (size_t)li * 8) = v;
}

// ---- Layer 1: INRF(3->192, 32x32) + fused 2x2 maxpool -> x00 + padded x00p  (verified)
__global__ __launch_bounds__(256, 3) void inrf1_mfma(
    const float* __restrict__ x, const __bf16* __restrict__ Bp,
    const float* __restrict__ bias, float* __restrict__ x00,
    float* __restrict__ x00p)
{
    __shared__ float win[3][6][36];
    __shared__ float hp[192][33];

    const int b  = blockIdx.x >> 4;
    const int h0 = (blockIdx.x & 15) * 2;
    const int tid = threadIdx.x;
    const int wv = tid >> 6, lane = tid & 63;
    const int hl = wv >> 1, half = wv & 1;
    const int mcol = lane & 15, q = lane >> 4;
    const int wpos = half * 16 + mcol;

    for (int i = tid; i < 3 * 6 * 36; i += 256) {
        int c = i / 216, r = (i / 36) % 6, cc = i % 36;
        int gr = h0 + r - 2, gc = cc - 2;
        float v = 0.f;
        if (gr >= 0 && gr < 32 && gc >= 0 && gc < 32)
            v = x[((size_t)(b * 3 + c) * 32 + gr) * 32 + gc];
        win[c][r][cc] = v;
    }
    __syncthreads();

    int offs[8];
    #pragma unroll
    for (int e = 0; e < 8; ++e) {
        int k = q * 8 + e;
        int kk = (k < 25) ? k : 0;      // pad elems hit B-weight zeros; value don't-care
        offs[e] = (hl + kk / 5) * 36 + wpos + (kk % 5);
    }
    const int cen_off = (hl + 2) * 36 + wpos + 2;

    f32x4 acc[NF];
    #pragma unroll
    for (int j = 0; j < NF; ++j) acc[j] = (f32x4){0.f, 0.f, 0.f, 0.f};

    const float* winf = &win[0][0][0];
    for (int c = 0; c < 3; ++c) {
        const float* wf = winf + c * 216;
        float cenc = wf[cen_off] * TSC;
        bf16_8 av, as_;
        #pragma unroll
        for (int e = 0; e < 8; ++e) {
            float v = wf[offs[e]];
            av[e] = (__bf16)v;
            as_[e] = (__bf16)fast_tanh_f(v, cenc);
        }
        const bf16_8* b0 = (const bf16_8*)Bp + ((size_t)(c * 2 + 0) * NF) * 64 + lane;
        const bf16_8* b1 = b0 + NF * 64;
        #pragma unroll
        for (int j = 0; j < NF; ++j)
            acc[j] = __builtin_amdgcn_mfma_f32_16x16x32_bf16(av, b0[j * 64], acc[j], 0, 0, 0);
        #pragma unroll
        for (int j = 0; j < NF; ++j)
            acc[j] = __builtin_amdgcn_mfma_f32_16x16x32_bf16(as_, b1[j * 64], acc[j], 0, 0, 0);
    }

    #pragma unroll
    for (int j = 0; j < NF; ++j) {
        int n = j * 16 + mcol;
        hp[n][hl * 16 + half * 8 + q * 2 + 0] = fmaxf(acc[j][0], acc[j][1]);
        hp[n][hl * 16 + half * 8 + q * 2 + 1] = fmaxf(acc[j][2], acc[j][3]);
    }
    __syncthreads();

    const int hpout = h0 >> 1;
    for (int i = tid; i < 192 * 16; i += 256) {
        int n = i >> 4, wp = i & 15;
        float v = fmaxf(hp[n][wp], hp[n][16 + wp]) + bias[n];
        x00[((size_t)(b * COUT + n) * 16 + hpout) * 16 + wp] = v;
        x00p[(size_t)(b * COUT + n) * 400 + (hpout + 2) * 20 + (wp + 2)] = v;
    }
}

// ---- Layer 2: INRF(192->192, 16x16). NO LDS, NO barriers (R10 dataflow, M-split grid).
// Grid 1024 = 64 img x 4 ksO x 2 nb x 2 mb; 256 thr = 4 waves (wave = mg).
// Wave: 2 m-tiles (h rows mb*8 + mg*2 ..+1) x 6 N-frags x 48 channels.
// 4 blocks/CU x 4 waves = 16 waves/CU (VGPR cap 128; need ~110 -> no spill).
// A: JIT global loads from padded x00p (L1). B: global frag loads, reg double-buffer.
__global__ __launch_bounds__(256, 4) void inrf2_mfma(
    const float* __restrict__ x00p, const __bf16* __restrict__ Bp,
    float* __restrict__ out0, float* __restrict__ part)
{
    constexpr int CPS = 48;
    const int bid = blockIdx.x;
    const int b   = bid >> 4;
    const int ksO = (bid >> 2) & 3;
    const int nb  = (bid >> 1) & 1;
    const int mb  = bid & 1;
    const int c0  = ksO * CPS;
    const int tid = threadIdx.x;
    const int wv = tid >> 6, lane = tid & 63;   // wv = mg
    const int wp = lane & 15, q = lane >> 4;
    const int crow0 = mb * 8 + wv * 2;          // first h-row of this wave's 2 m-tiles

    // per-lane padded-slab offsets for m=0; m adds +m*20
    int goff[9];
    #pragma unroll
    for (int e = 0; e < 8; ++e) {
        int kk = q * 8 + e;
        int k2 = (kk < 25) ? kk : 12;           // k-pad -> center (weight is zero)
        int dy = k2 / 5 - 2, dx = k2 % 5 - 2;
        goff[e] = (crow0 + dy + 2) * 20 + (wp + dx + 2);
    }
    goff[8] = (crow0 + 2) * 20 + (wp + 2);      // center

    const float* xs = x00p + (size_t)(b * COUT + c0) * 400;
    const __bf16* Bb = Bp + (size_t)c0 * 12288 + (size_t)nb * 6 * 512 + (size_t)lane * 8;

    f32x4 acc[2][6];
    #pragma unroll
    for (int m = 0; m < 2; ++m)
        #pragma unroll
        for (int j = 0; j < 6; ++j) acc[m][j] = (f32x4){0.f, 0.f, 0.f, 0.f};

#define LOAD_B(c, DST)                                                     \
    {                                                                      \
        const __bf16* gB = Bb + (size_t)(c) * 12288;                       \
        _Pragma("unroll")                                                  \
        for (int j = 0; j < 6; ++j) {                                      \
            (DST)[j]     = *(const bf16_8*)(gB + j * 512);                 \
            (DST)[6 + j] = *(const bf16_8*)(gB + 6144 + j * 512);          \
        }                                                                  \
    }

#define STEP(r, CB, NB)                                                    \
    {                                                                      \
        if ((r) + 1 < CPS) LOAD_B((r) + 1, NB);                            \
        const float* xc = xs + (size_t)(r) * 400;                          \
        bf16_8 av[2], as_[2];                                              \
        _Pragma("unroll")                                                  \
        for (int m = 0; m < 2; ++m) {                                      \
            float raw[9];                                                  \
            _Pragma("unroll")                                              \
            for (int i = 0; i < 9; ++i) raw[i] = xc[goff[i] + m * 20];     \
            float cenc = raw[8] * TSC;                                     \
            _Pragma("unroll")                                              \
            for (int e = 0; e < 8; ++e) {                                  \
                av[m][e] = (__bf16)raw[e];                                 \
                as_[m][e] = (__bf16)fast_tanh_f(raw[e], cenc);             \
            }                                                              \
        }                                                                  \
        _Pragma("unroll")                                                  \
        for (int j = 0; j < 6; ++j) {                                      \
            _Pragma("unroll")                                              \
            for (int m = 0; m < 2; ++m) {                                  \
                acc[m][j] = __builtin_amdgcn_mfma_f32_16x16x32_bf16(av[m],  (CB)[j],     acc[m][j], 0, 0, 0); \
                acc[m][j] = __builtin_amdgcn_mfma_f32_16x16x32_bf16(as_[m], (CB)[6 + j], acc[m][j], 0, 0, 0); \
            }                                                              \
        }                                                                  \
    }

    bf16_8 bufA[12], bufB[12];
    LOAD_B(0, bufA);
    for (int r2 = 0; r2 < CPS / 2; ++r2) {
        STEP(2 * r2,     bufA, bufB);
        STEP(2 * r2 + 1, bufB, bufA);
    }
#undef STEP
#undef LOAD_B

    // ---- epilogue: plain coalesced f32x4 stores
    float* outp = (ksO == 0) ? out0 : (part + (size_t)(ksO - 1) * 3145728);
    #pragma unroll
    for (int j = 0; j < 6; ++j) {
        int n = (nb * 6 + j) * 16 + wp;
        #pragma unroll
        for (int m = 0; m < 2; ++m) {
            int h = crow0 + m;
            *(f32x4*)&outp[((size_t)(b * COUT + n)) * 256 + h * 16 + q * 4] = acc[m][j];
        }
    }
}

// ---- finish2: fixed-order partial reduce (+bias) -> x01 write; then maxpool(8x8)
// -> region-sums W, tanh-sums T -> An (bf16 A-frags, /64)
__global__ __launch_bounds__(512) void finish2(
    float* __restrict__ x01, const float* __restrict__ part,
    const float* __restrict__ bias, __bf16* __restrict__ An)
{
    __shared__ float xbuf[8][256];
    const int b  = blockIdx.x / 24;
    const int cg = blockIdx.x % 24;
    const int tid = threadIdx.x;
    const int wv = tid >> 6, lane = tid & 63;
    const int ch = cg * 8 + wv;

    float* p0 = x01 + ((size_t)b * COUT + ch) * 256;
    const float* pp = part + ((size_t)b * COUT + ch) * 256;
    const float bv = bias[ch];
    #pragma unroll
    for (int i = 0; i < 4; ++i) {
        int idx = lane + 64 * i;
        float s = ((p0[idx] + pp[idx]) + pp[idx + 3145728]) + pp[idx + 2 * 3145728] + bv;
        xbuf[wv][idx] = s;
        p0[idx] = s;
    }
    __syncthreads();

    const int ph = lane >> 3, pw = lane & 7;
    const int i0 = ph * 32 + pw * 2;
    float x8 = fmaxf(fmaxf(xbuf[wv][i0], xbuf[wv][i0 + 1]),
                     fmaxf(xbuf[wv][i0 + 16], xbuf[wv][i0 + 17]));
    const float cenc = x8 * TSC;

    float myT = 0.f, myW = 0.f;
    #pragma unroll
    for (int k = 0; k < 25; ++k) {
        const int dy = k / 5 - 2, dx = k % 5 - 2;
        const bool valid = (ph + dy >= 0) && (ph + dy < 8) && (pw + dx >= 0) && (pw + dx < 8);
        float nb = __shfl(x8, (lane + dy * 8 + dx) & 63);
        nb = valid ? nb : 0.f;
        float tS = fast_tanh_f(nb, cenc);
        float wS = nb;
        #pragma unroll
        for (int off = 1; off < 64; off <<= 1) {
            tS += __shfl_xor(tS, off);
            wS += __shfl_xor(wS, off);
        }
        if (lane == k) { myT = tS; myW = wS; }
    }

    const int mt = b >> 4;
    if (lane < 25) {
        const int k = lane;
        const int la = (k >> 3) * 16 + (b & 15);
        const int e = k & 7;
        const int ccW = ch * 2, ccT = ch * 2 + 1;
        An[((size_t)(ccW * 4 + mt) * 64 + la) * 8 + e] = (__bf16)(myW * 0.015625f);
        An[((size_t)(ccT * 4 + mt) * 64 + la) * 8 + e] = (__bf16)(myT * 0.015625f);
    } else if (lane < 32) {
        // zero-fill padding slots (k=25..31) for determinism (ws is poisoned, not zeroed)
        const int la = 3 * 16 + (b & 15);
        const int e = lane & 7;
        const int ccW = ch * 2, ccT = ch * 2 + 1;
        An[((size_t)(ccW * 4 + mt) * 64 + la) * 8 + e] = (__bf16)0.f;
        An[((size_t)(ccT * 4 + mt) * 64 + la) * 8 + e] = (__bf16)0.f;
    }
}

// ---- tiny GEMM: feat-partials [96][192][64] = An[64 x 12288] * Bp3[12288 x 192]
__global__ __launch_bounds__(512) void gemm3p(
    const __bf16* __restrict__ An, const __bf16* __restrict__ Bp,
    float* __restrict__ part)
{
    const int ks = blockIdx.x;          // 96 blocks, 4 cc each
    const int tid = threadIdx.x;
    const int wv = tid >> 6, lane = tid & 63;
    const int mt = wv & 3, nh = wv >> 2;

    f32x4 acc[6];
    #pragma unroll
    for (int j = 0; j < 6; ++j) acc[j] = (f32x4){0.f, 0.f, 0.f, 0.f};

    for (int i = 0; i < 4; ++i) {
        const int cc = ks * 4 + i;
        bf16_8 a = *(const bf16_8*)(An + ((size_t)(cc * 4 + mt) * 64 + lane) * 8);
        #pragma unroll
        for (int j = 0; j < 6; ++j) {
            bf16_8 bw = *(const bf16_8*)(Bp + ((size_t)(cc * NF + nh * 6 + j) * 64 + lane) * 8);
            acc[j] = __builtin_amdgcn_mfma_f32_16x16x32_bf16(a, bw, acc[j], 0, 0, 0);
        }
    }
    #pragma unroll
    for (int j = 0; j < 6; ++j) {
        int n = (nh * 6 + j) * 16 + (lane & 15);
        *(f32x4*)(part + ((size_t)ks * COUT + n) * 64 + mt * 16 + (lane >> 4) * 4) = acc[j];
    }
}

// ---- logits: feat = sum of 96 partials + m3_b; logits = feat @ fc_w^T + fc_b
__global__ __launch_bounds__(256) void logitsk(
    const float* __restrict__ part, const float* __restrict__ m3_b,
    const float* __restrict__ fc_w, const float* __restrict__ fc_b,
    float* __restrict__ logits)
{
    __shared__ float feat[COUT];
    const int b = blockIdx.x;
    const int t = threadIdx.x;
    if (t < COUT) {
        float s = 0.f;
        for (int ks = 0; ks < 96; ++ks) s += part[((size_t)ks * COUT + t) * 64 + b];
        feat[t] = s + m3_b[t];
    }
    __syncthreads();
    if (t < 10) {
        float s = fc_b[t];
        #pragma unroll 8
        for (int c = 0; c < COUT; ++c) s = fmaf(fc_w[t * COUT + c], feat[c], s);
        logits[(size_t)b * 10 + t] = s;
    }
}

extern "C" void kernel_launch(void* const* d_in, const int* in_sizes, int n_in,
                              void* d_out, int out_size, void* d_ws, size_t ws_size,
                              hipStream_t stream) {
    const float* x    = (const float*)d_in[0];
    const float* m1_w = (const float*)d_in[1];
    const float* m1_b = (const float*)d_in[2];
    const float* w1_w = (const float*)d_in[3];
    const float* m2_w = (const float*)d_in[4];
    const float* m2_b = (const float*)d_in[5];
    const float* w2_w = (const float*)d_in[6];
    const float* m3_w = (const float*)d_in[7];
    const float* m3_b = (const float*)d_in[8];
    const float* w3_w = (const float*)d_in[9];
    const float* fc_w = (const float*)d_in[10];
    const float* fc_b = (const float*)d_in[11];

    float* out = (float*)d_out;
    float* ws  = (float*)d_ws;

    // d_out: [logits(640) | x00(3145728) | x01(3145728)]
    float* logits = out;
    float* x00 = out + 640;
    float* x01 = out + 640 + 3145728;

    // ws (float units):
    __bf16* Bp1  = (__bf16*)(ws);                //    36,864 bf16 (18,432 f)
    __bf16* Bp2  = (__bf16*)(ws + 18432);        // 2,359,296 bf16 (1,179,648 f)
    __bf16* Bp3  = (__bf16*)(ws + 1198080);      // 2,359,296 bf16 (1,179,648 f)
    __bf16* An   = (__bf16*)(ws + 2377728);      //   786,432 bf16 (393,216 f)
    float*  part2 = ws + 2770944;                // 9,437,184 f32 (ks=1..3 partials)
    float*  part3 = ws + 2770944;                // 1,179,648 f32 (ALIAS: written after part2's last read)
    float*  x00p  = ws + 12208128;               // 4,915,200 f32 padded slabs [b][c][20][20]
                                                 // total 17,123,328 f = 68.5 MB

    prep_all<<<7122, 256, 0, stream>>>(m1_w, w1_w, m2_w, w2_w, m3_w, w3_w,
                                       Bp1, Bp2, Bp3, x00p);

    inrf1_mfma<<<64 * 16, 256, 0, stream>>>(x, Bp1, m1_b, x00, x00p);
    inrf2_mfma<<<64 * 16, 256, 0, stream>>>(x00p, Bp2, x01, part2);
    finish2<<<64 * 24, 512, 0, stream>>>(x01, part2, m2_b, An);
    gemm3p<<<96, 512, 0, stream>>>(An, Bp3, part3);
    logitsk<<<64, 256, 0, stream>>>(part3, m3_b, fc_w, fc_b, logits);
}

// Round 14
// 225.737 us; speedup vs baseline: 1.8307x; 1.8307x over previous
//
#include <hip/hip_runtime.h>
#include <math.h>

#define COUT 192
#define NF 12
#define TSC 36.06737602222409f     // tanh(12.5 d) = 1 - 2/(exp2(TSC*d)+1)

typedef __bf16 bf16_8 __attribute__((ext_vector_type(8)));
typedef float  f32x4  __attribute__((ext_vector_type(4)));

__device__ __forceinline__ float fast_tanh_f(float v, float cenc) {
    float e = __builtin_amdgcn_exp2f(__builtin_fmaf(v, TSC, -cenc));
    return 1.0f - 2.0f * __builtin_amdgcn_rcpf(e + 1.0f);
}

// ---- merged weight prep + x00p zero-fill.
// Bp[(cc*NF+nf)*64 + lane][8] bf16; cc=c*2+t, k=(lane>>4)*8+e, n=nf*16+(lane&15);
// t=0 -> m_w, t=1 -> -2*w_w; k>=25 zero-pad.
__global__ void prep_all(const float* __restrict__ m1_w, const float* __restrict__ w1_w,
                         const float* __restrict__ m2_w, const float* __restrict__ w2_w,
                         const float* __restrict__ m3_w, const float* __restrict__ w3_w,
                         __bf16* __restrict__ Bp1, __bf16* __restrict__ Bp2,
                         __bf16* __restrict__ Bp3, float* __restrict__ x00p) {
    int idx = blockIdx.x * 256 + threadIdx.x;
    const int N1 = 3 * 2 * NF * 64, N2 = 192 * 2 * NF * 64;
    const int NW = N1 + 2 * N2;
    if (idx >= NW) {
        int zi = idx - NW;                       // zero x00p: 12288*400 floats as float4
        if (zi < 1228800) ((f32x4*)x00p)[zi] = (f32x4){0.f, 0.f, 0.f, 0.f};
        return;
    }
    const float *mw, *ww; __bf16* Bp; int CIN, li;
    if (idx < N1)           { mw = m1_w; ww = w1_w; Bp = Bp1; CIN = 3;   li = idx; }
    else if (idx < N1 + N2) { mw = m2_w; ww = w2_w; Bp = Bp2; CIN = 192; li = idx - N1; }
    else                    { mw = m3_w; ww = w3_w; Bp = Bp3; CIN = 192; li = idx - N1 - N2; }
    int lane = li & 63;
    int nf = (li >> 6) % NF;
    int cc = li / (NF * 64);
    int t = cc & 1, c = cc >> 1;
    int n = nf * 16 + (lane & 15);
    int k0 = (lane >> 4) * 8;
    bf16_8 v;
    #pragma unroll
    for (int e = 0; e < 8; ++e) {
        int k = k0 + e;
        float val = 0.f;
        if (k < 25) {
            val = (t == 0) ? mw[((size_t)n * CIN + c) * 25 + k]
                           : -2.0f * ww[((size_t)n * CIN + c) * 25 + k];
        }
        v[e] = (__bf16)val;
    }
    *(bf16_8*)(Bp + (size_t)li * 8) = v;
}

// ---- Layer 1: INRF(3->192, 32x32) + fused 2x2 maxpool -> x00 + padded x00p  (verified)
__global__ __launch_bounds__(256, 3) void inrf1_mfma(
    const float* __restrict__ x, const __bf16* __restrict__ Bp,
    const float* __restrict__ bias, float* __restrict__ x00,
    float* __restrict__ x00p)
{
    __shared__ float win[3][6][36];
    __shared__ float hp[192][33];

    const int b  = blockIdx.x >> 4;
    const int h0 = (blockIdx.x & 15) * 2;
    const int tid = threadIdx.x;
    const int wv = tid >> 6, lane = tid & 63;
    const int hl = wv >> 1, half = wv & 1;
    const int mcol = lane & 15, q = lane >> 4;
    const int wpos = half * 16 + mcol;

    for (int i = tid; i < 3 * 6 * 36; i += 256) {
        int c = i / 216, r = (i / 36) % 6, cc = i % 36;
        int gr = h0 + r - 2, gc = cc - 2;
        float v = 0.f;
        if (gr >= 0 && gr < 32 && gc >= 0 && gc < 32)
            v = x[((size_t)(b * 3 + c) * 32 + gr) * 32 + gc];
        win[c][r][cc] = v;
    }
    __syncthreads();

    int offs[8];
    #pragma unroll
    for (int e = 0; e < 8; ++e) {
        int k = q * 8 + e;
        int kk = (k < 25) ? k : 0;      // pad elems hit B-weight zeros; value don't-care
        offs[e] = (hl + kk / 5) * 36 + wpos + (kk % 5);
    }
    const int cen_off = (hl + 2) * 36 + wpos + 2;

    f32x4 acc[NF];
    #pragma unroll
    for (int j = 0; j < NF; ++j) acc[j] = (f32x4){0.f, 0.f, 0.f, 0.f};

    const float* winf = &win[0][0][0];
    for (int c = 0; c < 3; ++c) {
        const float* wf = winf + c * 216;
        float cenc = wf[cen_off] * TSC;
        bf16_8 av, as_;
        #pragma unroll
        for (int e = 0; e < 8; ++e) {
            float v = wf[offs[e]];
            av[e] = (__bf16)v;
            as_[e] = (__bf16)fast_tanh_f(v, cenc);
        }
        const bf16_8* b0 = (const bf16_8*)Bp + ((size_t)(c * 2 + 0) * NF) * 64 + lane;
        const bf16_8* b1 = b0 + NF * 64;
        #pragma unroll
        for (int j = 0; j < NF; ++j)
            acc[j] = __builtin_amdgcn_mfma_f32_16x16x32_bf16(av, b0[j * 64], acc[j], 0, 0, 0);
        #pragma unroll
        for (int j = 0; j < NF; ++j)
            acc[j] = __builtin_amdgcn_mfma_f32_16x16x32_bf16(as_, b1[j * 64], acc[j], 0, 0, 0);
    }

    #pragma unroll
    for (int j = 0; j < NF; ++j) {
        int n = j * 16 + mcol;
        hp[n][hl * 16 + half * 8 + q * 2 + 0] = fmaxf(acc[j][0], acc[j][1]);
        hp[n][hl * 16 + half * 8 + q * 2 + 1] = fmaxf(acc[j][2], acc[j][3]);
    }
    __syncthreads();

    const int hpout = h0 >> 1;
    for (int i = tid; i < 192 * 16; i += 256) {
        int n = i >> 4, wp = i & 15;
        float v = fmaxf(hp[n][wp], hp[n][16 + wp]) + bias[n];
        x00[((size_t)(b * COUT + n) * 16 + hpout) * 16 + wp] = v;
        x00p[(size_t)(b * COUT + n) * 400 + (hpout + 2) * 20 + (wp + 2)] = v;
    }
}

// ---- Layer 2: INRF(192->192, 16x16). NO LDS, NO barriers (R10 dataflow, M-split grid).
// Grid 1024 = 64 img x 4 ksO x 2 nb x 2 mb; 256 thr = 4 waves (wave = mg).
// Wave: 2 m-tiles (h rows mb*8 + mg*2 ..+1) x 6 N-frags x 48 channels.
// __launch_bounds__(256, 2): empirical arch-VGPR cap 128 (w=4 capped at 64 -> spill,
// R11/R13). Runtime occupancy set by actual usage -> 3-4 blocks/CU with grid 1024.
// A: JIT global loads from padded x00p (L1). B: global frag loads, reg double-buffer.
__global__ __launch_bounds__(256, 2) void inrf2_mfma(
    const float* __restrict__ x00p, const __bf16* __restrict__ Bp,
    float* __restrict__ out0, float* __restrict__ part)
{
    constexpr int CPS = 48;
    const int bid = blockIdx.x;
    const int b   = bid >> 4;
    const int ksO = (bid >> 2) & 3;
    const int nb  = (bid >> 1) & 1;
    const int mb  = bid & 1;
    const int c0  = ksO * CPS;
    const int tid = threadIdx.x;
    const int wv = tid >> 6, lane = tid & 63;   // wv = mg
    const int wp = lane & 15, q = lane >> 4;
    const int crow0 = mb * 8 + wv * 2;          // first h-row of this wave's 2 m-tiles

    // per-lane padded-slab offsets for m=0; m adds +m*20
    int goff[9];
    #pragma unroll
    for (int e = 0; e < 8; ++e) {
        int kk = q * 8 + e;
        int k2 = (kk < 25) ? kk : 12;           // k-pad -> center (weight is zero)
        int dy = k2 / 5 - 2, dx = k2 % 5 - 2;
        goff[e] = (crow0 + dy + 2) * 20 + (wp + dx + 2);
    }
    goff[8] = (crow0 + 2) * 20 + (wp + 2);      // center

    const float* xs = x00p + (size_t)(b * COUT + c0) * 400;
    const __bf16* Bb = Bp + (size_t)c0 * 12288 + (size_t)nb * 6 * 512 + (size_t)lane * 8;

    f32x4 acc[2][6];
    #pragma unroll
    for (int m = 0; m < 2; ++m)
        #pragma unroll
        for (int j = 0; j < 6; ++j) acc[m][j] = (f32x4){0.f, 0.f, 0.f, 0.f};

#define LOAD_B(c, DST)                                                     \
    {                                                                      \
        const __bf16* gB = Bb + (size_t)(c) * 12288;                       \
        _Pragma("unroll")                                                  \
        for (int j = 0; j < 6; ++j) {                                      \
            (DST)[j]     = *(const bf16_8*)(gB + j * 512);                 \
            (DST)[6 + j] = *(const bf16_8*)(gB + 6144 + j * 512);          \
        }                                                                  \
    }

#define STEP(r, CB, NB)                                                    \
    {                                                                      \
        if ((r) + 1 < CPS) LOAD_B((r) + 1, NB);                            \
        const float* xc = xs + (size_t)(r) * 400;                          \
        bf16_8 av[2], as_[2];                                              \
        _Pragma("unroll")                                                  \
        for (int m = 0; m < 2; ++m) {                                      \
            float raw[9];                                                  \
            _Pragma("unroll")                                              \
            for (int i = 0; i < 9; ++i) raw[i] = xc[goff[i] + m * 20];     \
            float cenc = raw[8] * TSC;                                     \
            _Pragma("unroll")                                              \
            for (int e = 0; e < 8; ++e) {                                  \
                av[m][e] = (__bf16)raw[e];                                 \
                as_[m][e] = (__bf16)fast_tanh_f(raw[e], cenc);             \
            }                                                              \
        }                                                                  \
        _Pragma("unroll")                                                  \
        for (int j = 0; j < 6; ++j) {                                      \
            _Pragma("unroll")                                              \
            for (int m = 0; m < 2; ++m) {                                  \
                acc[m][j] = __builtin_amdgcn_mfma_f32_16x16x32_bf16(av[m],  (CB)[j],     acc[m][j], 0, 0, 0); \
                acc[m][j] = __builtin_amdgcn_mfma_f32_16x16x32_bf16(as_[m], (CB)[6 + j], acc[m][j], 0, 0, 0); \
            }                                                              \
        }                                                                  \
    }

    bf16_8 bufA[12], bufB[12];
    LOAD_B(0, bufA);
    for (int r2 = 0; r2 < CPS / 2; ++r2) {
        STEP(2 * r2,     bufA, bufB);
        STEP(2 * r2 + 1, bufB, bufA);
    }
#undef STEP
#undef LOAD_B

    // ---- epilogue: plain coalesced f32x4 stores
    float* outp = (ksO == 0) ? out0 : (part + (size_t)(ksO - 1) * 3145728);
    #pragma unroll
    for (int j = 0; j < 6; ++j) {
        int n = (nb * 6 + j) * 16 + wp;
        #pragma unroll
        for (int m = 0; m < 2; ++m) {
            int h = crow0 + m;
            *(f32x4*)&outp[((size_t)(b * COUT + n)) * 256 + h * 16 + q * 4] = acc[m][j];
        }
    }
}

// ---- finish2: fixed-order partial reduce (+bias) -> x01 write; then maxpool(8x8)
// -> region-sums W, tanh-sums T -> An (bf16 A-frags, /64)
__global__ __launch_bounds__(512) void finish2(
    float* __restrict__ x01, const float* __restrict__ part,
    const float* __restrict__ bias, __bf16* __restrict__ An)
{
    __shared__ float xbuf[8][256];
    const int b  = blockIdx.x / 24;
    const int cg = blockIdx.x % 24;
    const int tid = threadIdx.x;
    const int wv = tid >> 6, lane = tid & 63;
    const int ch = cg * 8 + wv;

    float* p0 = x01 + ((size_t)b * COUT + ch) * 256;
    const float* pp = part + ((size_t)b * COUT + ch) * 256;
    const float bv = bias[ch];
    #pragma unroll
    for (int i = 0; i < 4; ++i) {
        int idx = lane + 64 * i;
        float s = ((p0[idx] + pp[idx]) + pp[idx + 3145728]) + pp[idx + 2 * 3145728] + bv;
        xbuf[wv][idx] = s;
        p0[idx] = s;
    }
    __syncthreads();

    const int ph = lane >> 3, pw = lane & 7;
    const int i0 = ph * 32 + pw * 2;
    float x8 = fmaxf(fmaxf(xbuf[wv][i0], xbuf[wv][i0 + 1]),
                     fmaxf(xbuf[wv][i0 + 16], xbuf[wv][i0 + 17]));
    const float cenc = x8 * TSC;

    float myT = 0.f, myW = 0.f;
    #pragma unroll
    for (int k = 0; k < 25; ++k) {
        const int dy = k / 5 - 2, dx = k % 5 - 2;
        const bool valid = (ph + dy >= 0) && (ph + dy < 8) && (pw + dx >= 0) && (pw + dx < 8);
        float nb = __shfl(x8, (lane + dy * 8 + dx) & 63);
        nb = valid ? nb : 0.f;
        float tS = fast_tanh_f(nb, cenc);
        float wS = nb;
        #pragma unroll
        for (int off = 1; off < 64; off <<= 1) {
            tS += __shfl_xor(tS, off);
            wS += __shfl_xor(wS, off);
        }
        if (lane == k) { myT = tS; myW = wS; }
    }

    const int mt = b >> 4;
    if (lane < 25) {
        const int k = lane;
        const int la = (k >> 3) * 16 + (b & 15);
        const int e = k & 7;
        const int ccW = ch * 2, ccT = ch * 2 + 1;
        An[((size_t)(ccW * 4 + mt) * 64 + la) * 8 + e] = (__bf16)(myW * 0.015625f);
        An[((size_t)(ccT * 4 + mt) * 64 + la) * 8 + e] = (__bf16)(myT * 0.015625f);
    } else if (lane < 32) {
        // zero-fill padding slots (k=25..31) for determinism (ws is poisoned, not zeroed)
        const int la = 3 * 16 + (b & 15);
        const int e = lane & 7;
        const int ccW = ch * 2, ccT = ch * 2 + 1;
        An[((size_t)(ccW * 4 + mt) * 64 + la) * 8 + e] = (__bf16)0.f;
        An[((size_t)(ccT * 4 + mt) * 64 + la) * 8 + e] = (__bf16)0.f;
    }
}

// ---- tiny GEMM: feat-partials [96][192][64] = An[64 x 12288] * Bp3[12288 x 192]
__global__ __launch_bounds__(512) void gemm3p(
    const __bf16* __restrict__ An, const __bf16* __restrict__ Bp,
    float* __restrict__ part)
{
    const int ks = blockIdx.x;          // 96 blocks, 4 cc each
    const int tid = threadIdx.x;
    const int wv = tid >> 6, lane = tid & 63;
    const int mt = wv & 3, nh = wv >> 2;

    f32x4 acc[6];
    #pragma unroll
    for (int j = 0; j < 6; ++j) acc[j] = (f32x4){0.f, 0.f, 0.f, 0.f};

    for (int i = 0; i < 4; ++i) {
        const int cc = ks * 4 + i;
        bf16_8 a = *(const bf16_8*)(An + ((size_t)(cc * 4 + mt) * 64 + lane) * 8);
        #pragma unroll
        for (int j = 0; j < 6; ++j) {
            bf16_8 bw = *(const bf16_8*)(Bp + ((size_t)(cc * NF + nh * 6 + j) * 64 + lane) * 8);
            acc[j] = __builtin_amdgcn_mfma_f32_16x16x32_bf16(a, bw, acc[j], 0, 0, 0);
        }
    }
    #pragma unroll
    for (int j = 0; j < 6; ++j) {
        int n = (nh * 6 + j) * 16 + (lane & 15);
        *(f32x4*)(part + ((size_t)ks * COUT + n) * 64 + mt * 16 + (lane >> 4) * 4) = acc[j];
    }
}

// ---- logits: feat = sum of 96 partials + m3_b; logits = feat @ fc_w^T + fc_b
__global__ __launch_bounds__(256) void logitsk(
    const float* __restrict__ part, const float* __restrict__ m3_b,
    const float* __restrict__ fc_w, const float* __restrict__ fc_b,
    float* __restrict__ logits)
{
    __shared__ float feat[COUT];
    const int b = blockIdx.x;
    const int t = threadIdx.x;
    if (t < COUT) {
        float s = 0.f;
        for (int ks = 0; ks < 96; ++ks) s += part[((size_t)ks * COUT + t) * 64 + b];
        feat[t] = s + m3_b[t];
    }
    __syncthreads();
    if (t < 10) {
        float s = fc_b[t];
        #pragma unroll 8
        for (int c = 0; c < COUT; ++c) s = fmaf(fc_w[t * COUT + c], feat[c], s);
        logits[(size_t)b * 10 + t] = s;
    }
}

extern "C" void kernel_launch(void* const* d_in, const int* in_sizes, int n_in,
                              void* d_out, int out_size, void* d_ws, size_t ws_size,
                              hipStream_t stream) {
    const float* x    = (const float*)d_in[0];
    const float* m1_w = (const float*)d_in[1];
    const float* m1_b = (const float*)d_in[2];
    const float* w1_w = (const float*)d_in[3];
    const float* m2_w = (const float*)d_in[4];
    const float* m2_b = (const float*)d_in[5];
    const float* w2_w = (const float*)d_in[6];
    const float* m3_w = (const float*)d_in[7];
    const float* m3_b = (const float*)d_in[8];
    const float* w3_w = (const float*)d_in[9];
    const float* fc_w = (const float*)d_in[10];
    const float* fc_b = (const float*)d_in[11];

    float* out = (float*)d_out;
    float* ws  = (float*)d_ws;

    // d_out: [logits(640) | x00(3145728) | x01(3145728)]
    float* logits = out;
    float* x00 = out + 640;
    float* x01 = out + 640 + 3145728;

    // ws (float units):
    __bf16* Bp1  = (__bf16*)(ws);                //    36,864 bf16 (18,432 f)
    __bf16* Bp2  = (__bf16*)(ws + 18432);        // 2,359,296 bf16 (1,179,648 f)
    __bf16* Bp3  = (__bf16*)(ws + 1198080);      // 2,359,296 bf16 (1,179,648 f)
    __bf16* An   = (__bf16*)(ws + 2377728);      //   786,432 bf16 (393,216 f)
    float*  part2 = ws + 2770944;                // 9,437,184 f32 (ks=1..3 partials)
    float*  part3 = ws + 2770944;                // 1,179,648 f32 (ALIAS: written after part2's last read)
    float*  x00p  = ws + 12208128;               // 4,915,200 f32 padded slabs [b][c][20][20]
                                                 // total 17,123,328 f = 68.5 MB

    prep_all<<<7122, 256, 0, stream>>>(m1_w, w1_w, m2_w, w2_w, m3_w, w3_w,
                                       Bp1, Bp2, Bp3, x00p);

    inrf1_mfma<<<64 * 16, 256, 0, stream>>>(x, Bp1, m1_b, x00, x00p);
    inrf2_mfma<<<64 * 16, 256, 0, stream>>>(x00p, Bp2, x01, part2);
    finish2<<<64 * 24, 512, 0, stream>>>(x01, part2, m2_b, An);
    gemm3p<<<96, 512, 0, stream>>>(An, Bp3, part3);
    logitsk<<<64, 256, 0, stream>>>(part3, m3_b, fc_w, fc_b, logits);
}

// Round 15
// 211.168 us; speedup vs baseline: 1.9570x; 1.0690x over previous
//
#include <hip/hip_runtime.h>
#include <math.h>

#define COUT 192
#define NF 12
#define TSC 36.06737602222409f     // tanh(12.5 d) = 1 - 2/(exp2(TSC*d)+1)

typedef __bf16 bf16_8 __attribute__((ext_vector_type(8)));
typedef float  f32x4  __attribute__((ext_vector_type(4)));

__device__ __forceinline__ float fast_tanh_f(float v, float cenc) {
    float e = __builtin_amdgcn_exp2f(__builtin_fmaf(v, TSC, -cenc));
    return 1.0f - 2.0f * __builtin_amdgcn_rcpf(e + 1.0f);
}

// ---- merged weight prep + x00p zero-fill.
// Bp[(cc*NF+nf)*64 + lane][8] bf16; cc=c*2+t, k=(lane>>4)*8+e, n=nf*16+(lane&15);
// t=0 -> m_w, t=1 -> -2*w_w; k>=25 zero-pad.
__global__ void prep_all(const float* __restrict__ m1_w, const float* __restrict__ w1_w,
                         const float* __restrict__ m2_w, const float* __restrict__ w2_w,
                         const float* __restrict__ m3_w, const float* __restrict__ w3_w,
                         __bf16* __restrict__ Bp1, __bf16* __restrict__ Bp2,
                         __bf16* __restrict__ Bp3, float* __restrict__ x00p) {
    int idx = blockIdx.x * 256 + threadIdx.x;
    const int N1 = 3 * 2 * NF * 64, N2 = 192 * 2 * NF * 64;
    const int NW = N1 + 2 * N2;
    if (idx >= NW) {
        int zi = idx - NW;                       // zero x00p: 12288*400 floats as float4
        if (zi < 1228800) ((f32x4*)x00p)[zi] = (f32x4){0.f, 0.f, 0.f, 0.f};
        return;
    }
    const float *mw, *ww; __bf16* Bp; int CIN, li;
    if (idx < N1)           { mw = m1_w; ww = w1_w; Bp = Bp1; CIN = 3;   li = idx; }
    else if (idx < N1 + N2) { mw = m2_w; ww = w2_w; Bp = Bp2; CIN = 192; li = idx - N1; }
    else                    { mw = m3_w; ww = w3_w; Bp = Bp3; CIN = 192; li = idx - N1 - N2; }
    int lane = li & 63;
    int nf = (li >> 6) % NF;
    int cc = li / (NF * 64);
    int t = cc & 1, c = cc >> 1;
    int n = nf * 16 + (lane & 15);
    int k0 = (lane >> 4) * 8;
    bf16_8 v;
    #pragma unroll
    for (int e = 0; e < 8; ++e) {
        int k = k0 + e;
        float val = 0.f;
        if (k < 25) {
            val = (t == 0) ? mw[((size_t)n * CIN + c) * 25 + k]
                           : -2.0f * ww[((size_t)n * CIN + c) * 25 + k];
        }
        v[e] = (__bf16)val;
    }
    *(bf16_8*)(Bp + (size_t)li * 8) = v;
}

// ---- Layer 1: INRF(3->192, 32x32) + fused 2x2 maxpool -> x00 + padded x00p  (verified)
__global__ __launch_bounds__(256, 3) void inrf1_mfma(
    const float* __restrict__ x, const __bf16* __restrict__ Bp,
    const float* __restrict__ bias, float* __restrict__ x00,
    float* __restrict__ x00p)
{
    __shared__ float win[3][6][36];
    __shared__ float hp[192][33];

    const int b  = blockIdx.x >> 4;
    const int h0 = (blockIdx.x & 15) * 2;
    const int tid = threadIdx.x;
    const int wv = tid >> 6, lane = tid & 63;
    const int hl = wv >> 1, half = wv & 1;
    const int mcol = lane & 15, q = lane >> 4;
    const int wpos = half * 16 + mcol;

    for (int i = tid; i < 3 * 6 * 36; i += 256) {
        int c = i / 216, r = (i / 36) % 6, cc = i % 36;
        int gr = h0 + r - 2, gc = cc - 2;
        float v = 0.f;
        if (gr >= 0 && gr < 32 && gc >= 0 && gc < 32)
            v = x[((size_t)(b * 3 + c) * 32 + gr) * 32 + gc];
        win[c][r][cc] = v;
    }
    __syncthreads();

    int offs[8];
    #pragma unroll
    for (int e = 0; e < 8; ++e) {
        int k = q * 8 + e;
        int kk = (k < 25) ? k : 0;      // pad elems hit B-weight zeros; value don't-care
        offs[e] = (hl + kk / 5) * 36 + wpos + (kk % 5);
    }
    const int cen_off = (hl + 2) * 36 + wpos + 2;

    f32x4 acc[NF];
    #pragma unroll
    for (int j = 0; j < NF; ++j) acc[j] = (f32x4){0.f, 0.f, 0.f, 0.f};

    const float* winf = &win[0][0][0];
    for (int c = 0; c < 3; ++c) {
        const float* wf = winf + c * 216;
        float cenc = wf[cen_off] * TSC;
        bf16_8 av, as_;
        #pragma unroll
        for (int e = 0; e < 8; ++e) {
            float v = wf[offs[e]];
            av[e] = (__bf16)v;
            as_[e] = (__bf16)fast_tanh_f(v, cenc);
        }
        const bf16_8* b0 = (const bf16_8*)Bp + ((size_t)(c * 2 + 0) * NF) * 64 + lane;
        const bf16_8* b1 = b0 + NF * 64;
        #pragma unroll
        for (int j = 0; j < NF; ++j)
            acc[j] = __builtin_amdgcn_mfma_f32_16x16x32_bf16(av, b0[j * 64], acc[j], 0, 0, 0);
        #pragma unroll
        for (int j = 0; j < NF; ++j)
            acc[j] = __builtin_amdgcn_mfma_f32_16x16x32_bf16(as_, b1[j * 64], acc[j], 0, 0, 0);
    }

    #pragma unroll
    for (int j = 0; j < NF; ++j) {
        int n = j * 16 + mcol;
        hp[n][hl * 16 + half * 8 + q * 2 + 0] = fmaxf(acc[j][0], acc[j][1]);
        hp[n][hl * 16 + half * 8 + q * 2 + 1] = fmaxf(acc[j][2], acc[j][3]);
    }
    __syncthreads();

    const int hpout = h0 >> 1;
    for (int i = tid; i < 192 * 16; i += 256) {
        int n = i >> 4, wp = i & 15;
        float v = fmaxf(hp[n][wp], hp[n][16 + wp]) + bias[n];
        x00[((size_t)(b * COUT + n) * 16 + hpout) * 16 + wp] = v;
        x00p[(size_t)(b * COUT + n) * 400 + (hpout + 2) * 20 + (wp + 2)] = v;
    }
}

// ---- Layer 2: INRF(192->192, 16x16). NO LDS, NO barriers (R10-proven dataflow).
// Grid 512 = 64 img x 4 ks x 2 nb; 256 thr = 4 waves (wave = mg, m_rep=4, 6 N-frags).
// A: JIT global loads from padded x00p (L1). B: global frag loads, reg double-buffer.
__global__ __launch_bounds__(256, 2) void inrf2_mfma(
    const float* __restrict__ x00p, const __bf16* __restrict__ Bp,
    float* __restrict__ out0, float* __restrict__ part)
{
    constexpr int CPS = 48;
    const int bid = blockIdx.x;
    const int b  = bid >> 3;
    const int ks = (bid >> 1) & 3;
    const int nb = bid & 1;
    const int c0 = ks * CPS;
    const int tid = threadIdx.x;
    const int wv = tid >> 6, lane = tid & 63;   // wv = mg
    const int wp = lane & 15, q = lane >> 4;

    // per-lane padded-slab offsets for m=0; m adds +m*20
    int goff[9];
    #pragma unroll
    for (int e = 0; e < 8; ++e) {
        int kk = q * 8 + e;
        int k2 = (kk < 25) ? kk : 12;           // k-pad -> center (weight is zero)
        int dy = k2 / 5 - 2, dx = k2 % 5 - 2;
        goff[e] = (wv * 4 + dy + 2) * 20 + (wp + dx + 2);
    }
    goff[8] = (wv * 4 + 2) * 20 + (wp + 2);     // center

    const float* xs = x00p + (size_t)(b * COUT + c0) * 400;
    const __bf16* Bb = Bp + (size_t)c0 * 12288 + (size_t)nb * 6 * 512 + (size_t)lane * 8;

    f32x4 acc[4][6];
    #pragma unroll
    for (int m = 0; m < 4; ++m)
        #pragma unroll
        for (int j = 0; j < 6; ++j) acc[m][j] = (f32x4){0.f, 0.f, 0.f, 0.f};

#define LOAD_B(c, DST)                                                     \
    {                                                                      \
        const __bf16* gB = Bb + (size_t)(c) * 12288;                       \
        _Pragma("unroll")                                                  \
        for (int j = 0; j < 6; ++j) {                                      \
            (DST)[j]     = *(const bf16_8*)(gB + j * 512);                 \
            (DST)[6 + j] = *(const bf16_8*)(gB + 6144 + j * 512);          \
        }                                                                  \
    }

#define STEP(r, CB, NB)                                                    \
    {                                                                      \
        if ((r) + 1 < CPS) LOAD_B((r) + 1, NB);                            \
        const float* xc = xs + (size_t)(r) * 400;                          \
        bf16_8 av[4], as_[4];                                              \
        _Pragma("unroll")                                                  \
        for (int m = 0; m < 4; ++m) {                                      \
            float raw[9];                                                  \
            _Pragma("unroll")                                              \
            for (int i = 0; i < 9; ++i) raw[i] = xc[goff[i] + m * 20];     \
            float cenc = raw[8] * TSC;                                     \
            _Pragma("unroll")                                              \
            for (int e = 0; e < 8; ++e) {                                  \
                av[m][e] = (__bf16)raw[e];                                 \
                as_[m][e] = (__bf16)fast_tanh_f(raw[e], cenc);             \
            }                                                              \
        }                                                                  \
        _Pragma("unroll")                                                  \
        for (int j = 0; j < 6; ++j) {                                      \
            _Pragma("unroll")                                              \
            for (int m = 0; m < 4; ++m) {                                  \
                acc[m][j] = __builtin_amdgcn_mfma_f32_16x16x32_bf16(av[m],  (CB)[j],     acc[m][j], 0, 0, 0); \
                acc[m][j] = __builtin_amdgcn_mfma_f32_16x16x32_bf16(as_[m], (CB)[6 + j], acc[m][j], 0, 0, 0); \
            }                                                              \
        }                                                                  \
    }

    bf16_8 bufA[12], bufB[12];
    LOAD_B(0, bufA);
    for (int r2 = 0; r2 < CPS / 2; ++r2) {
        STEP(2 * r2,     bufA, bufB);
        STEP(2 * r2 + 1, bufB, bufA);
    }
#undef STEP
#undef LOAD_B

    // ---- epilogue: plain coalesced f32x4 stores (this block's n-half)
    float* outp = (ks == 0) ? out0 : (part + (size_t)(ks - 1) * 3145728);
    #pragma unroll
    for (int j = 0; j < 6; ++j) {
        int n = (nb * 6 + j) * 16 + wp;
        #pragma unroll
        for (int m = 0; m < 4; ++m) {
            int h = wv * 4 + m;
            *(f32x4*)&outp[((size_t)(b * COUT + n)) * 256 + h * 16 + q * 4] = acc[m][j];
        }
    }
}

// ---- finish2: fixed-order partial reduce (+bias, f32x4) -> x01 write; in-register
// 2x2 maxpool -> region-sums W, tanh-sums T -> An (bf16 A-frags, /64)
__global__ __launch_bounds__(512) void finish2(
    float* __restrict__ x01, const float* __restrict__ part,
    const float* __restrict__ bias, __bf16* __restrict__ An)
{
    __shared__ float xp[8][64];
    const int b  = blockIdx.x / 24;
    const int cg = blockIdx.x % 24;
    const int tid = threadIdx.x;
    const int wv = tid >> 6, lane = tid & 63;
    const int ch = cg * 8 + wv;

    float* p0 = x01 + ((size_t)b * COUT + ch) * 256;
    const float* pp = part + ((size_t)b * COUT + ch) * 256;
    const float bv = bias[ch];

    // phase 1: vectorized fixed-order reduce + write (same add order as validated scalar)
    f32x4 v = ((const f32x4*)p0)[lane];
    v = v + ((const f32x4*)pp)[lane];
    v = v + ((const f32x4*)(pp + 3145728))[lane];
    v = v + ((const f32x4*)(pp + 2 * 3145728))[lane];
    v.x += bv; v.y += bv; v.z += bv; v.w += bv;
    ((f32x4*)p0)[lane] = v;

    // phase 2: in-register 2x2 maxpool. lane covers row r=lane>>2, cols (lane&3)*4..+3
    float h0 = fmaxf(v.x, v.y);                 // pooled col 2*(lane&3)
    float h1 = fmaxf(v.z, v.w);                 // pooled col 2*(lane&3)+1
    float o0 = __shfl_xor(h0, 4);               // partner row r^1
    float o1 = __shfl_xor(h1, 4);
    float q0 = fmaxf(h0, o0), q1 = fmaxf(h1, o1);
    if (!(lane & 4)) {                          // even rows hold pooled row lane>>3
        int base = (lane >> 3) * 8 + (lane & 3) * 2;
        xp[wv][base] = q0; xp[wv][base + 1] = q1;
    }
    // wave-private LDS: no barrier needed (compiler inserts lgkmcnt wait)
    float x8 = xp[wv][lane];
    const float cenc = x8 * TSC;

    const int ph = lane >> 3, pw = lane & 7;
    float myT = 0.f, myW = 0.f;
    #pragma unroll
    for (int k = 0; k < 25; ++k) {
        const int dy = k / 5 - 2, dx = k % 5 - 2;
        const bool valid = (ph + dy >= 0) && (ph + dy < 8) && (pw + dx >= 0) && (pw + dx < 8);
        float nb = __shfl(x8, (lane + dy * 8 + dx) & 63);
        nb = valid ? nb : 0.f;
        float tS = fast_tanh_f(nb, cenc);
        float wS = nb;
        #pragma unroll
        for (int off = 1; off < 64; off <<= 1) {
            tS += __shfl_xor(tS, off);
            wS += __shfl_xor(wS, off);
        }
        if (lane == k) { myT = tS; myW = wS; }
    }

    const int mt = b >> 4;
    if (lane < 25) {
        const int k = lane;
        const int la = (k >> 3) * 16 + (b & 15);
        const int e = k & 7;
        const int ccW = ch * 2, ccT = ch * 2 + 1;
        An[((size_t)(ccW * 4 + mt) * 64 + la) * 8 + e] = (__bf16)(myW * 0.015625f);
        An[((size_t)(ccT * 4 + mt) * 64 + la) * 8 + e] = (__bf16)(myT * 0.015625f);
    } else if (lane < 32) {
        // zero-fill padding slots (k=25..31) for determinism (ws is poisoned, not zeroed)
        const int la = 3 * 16 + (b & 15);
        const int e = lane & 7;
        const int ccW = ch * 2, ccT = ch * 2 + 1;
        An[((size_t)(ccW * 4 + mt) * 64 + la) * 8 + e] = (__bf16)0.f;
        An[((size_t)(ccT * 4 + mt) * 64 + la) * 8 + e] = (__bf16)0.f;
    }
}

// ---- tiny GEMM: feat-partials [96][192][64] = An[64 x 12288] * Bp3[12288 x 192]
__global__ __launch_bounds__(512) void gemm3p(
    const __bf16* __restrict__ An, const __bf16* __restrict__ Bp,
    float* __restrict__ part)
{
    const int ks = blockIdx.x;          // 96 blocks, 4 cc each
    const int tid = threadIdx.x;
    const int wv = tid >> 6, lane = tid & 63;
    const int mt = wv & 3, nh = wv >> 2;

    f32x4 acc[6];
    #pragma unroll
    for (int j = 0; j < 6; ++j) acc[j] = (f32x4){0.f, 0.f, 0.f, 0.f};

    for (int i = 0; i < 4; ++i) {
        const int cc = ks * 4 + i;
        bf16_8 a = *(const bf16_8*)(An + ((size_t)(cc * 4 + mt) * 64 + lane) * 8);
        #pragma unroll
        for (int j = 0; j < 6; ++j) {
            bf16_8 bw = *(const bf16_8*)(Bp + ((size_t)(cc * NF + nh * 6 + j) * 64 + lane) * 8);
            acc[j] = __builtin_amdgcn_mfma_f32_16x16x32_bf16(a, bw, acc[j], 0, 0, 0);
        }
    }
    #pragma unroll
    for (int j = 0; j < 6; ++j) {
        int n = (nh * 6 + j) * 16 + (lane & 15);
        *(f32x4*)(part + ((size_t)ks * COUT + n) * 64 + mt * 16 + (lane >> 4) * 4) = acc[j];
    }
}

// ---- logits: feat = sum of 96 partials (4-way ILP, fixed order) + m3_b; FC
__global__ __launch_bounds__(256) void logitsk(
    const float* __restrict__ part, const float* __restrict__ m3_b,
    const float* __restrict__ fc_w, const float* __restrict__ fc_b,
    float* __restrict__ logits)
{
    __shared__ float feat[COUT];
    const int b = blockIdx.x;
    const int t = threadIdx.x;
    if (t < COUT) {
        float s0 = 0.f, s1 = 0.f, s2 = 0.f, s3 = 0.f;
        for (int ks = 0; ks < 96; ks += 4) {
            s0 += part[((size_t)(ks + 0) * COUT + t) * 64 + b];
            s1 += part[((size_t)(ks + 1) * COUT + t) * 64 + b];
            s2 += part[((size_t)(ks + 2) * COUT + t) * 64 + b];
            s3 += part[((size_t)(ks + 3) * COUT + t) * 64 + b];
        }
        feat[t] = ((s0 + s1) + (s2 + s3)) + m3_b[t];
    }
    __syncthreads();
    if (t < 10) {
        float s = fc_b[t];
        #pragma unroll 8
        for (int c = 0; c < COUT; ++c) s = fmaf(fc_w[t * COUT + c], feat[c], s);
        logits[(size_t)b * 10 + t] = s;
    }
}

extern "C" void kernel_launch(void* const* d_in, const int* in_sizes, int n_in,
                              void* d_out, int out_size, void* d_ws, size_t ws_size,
                              hipStream_t stream) {
    const float* x    = (const float*)d_in[0];
    const float* m1_w = (const float*)d_in[1];
    const float* m1_b = (const float*)d_in[2];
    const float* w1_w = (const float*)d_in[3];
    const float* m2_w = (const float*)d_in[4];
    const float* m2_b = (const float*)d_in[5];
    const float* w2_w = (const float*)d_in[6];
    const float* m3_w = (const float*)d_in[7];
    const float* m3_b = (const float*)d_in[8];
    const float* w3_w = (const float*)d_in[9];
    const float* fc_w = (const float*)d_in[10];
    const float* fc_b = (const float*)d_in[11];

    float* out = (float*)d_out;
    float* ws  = (float*)d_ws;

    // d_out: [logits(640) | x00(3145728) | x01(3145728)]
    float* logits = out;
    float* x00 = out + 640;
    float* x01 = out + 640 + 3145728;

    // ws (float units):
    __bf16* Bp1  = (__bf16*)(ws);                //    36,864 bf16 (18,432 f)
    __bf16* Bp2  = (__bf16*)(ws + 18432);        // 2,359,296 bf16 (1,179,648 f)
    __bf16* Bp3  = (__bf16*)(ws + 1198080);      // 2,359,296 bf16 (1,179,648 f)
    __bf16* An   = (__bf16*)(ws + 2377728);      //   786,432 bf16 (393,216 f)
    float*  part2 = ws + 2770944;                // 9,437,184 f32 (ks=1..3 partials)
    float*  part3 = ws + 2770944;                // 1,179,648 f32 (ALIAS: written after part2's last read)
    float*  x00p  = ws + 12208128;               // 4,915,200 f32 padded slabs [b][c][20][20]
                                                 // total 17,123,328 f = 68.5 MB

    prep_all<<<7122, 256, 0, stream>>>(m1_w, w1_w, m2_w, w2_w, m3_w, w3_w,
                                       Bp1, Bp2, Bp3, x00p);

    inrf1_mfma<<<64 * 16, 256, 0, stream>>>(x, Bp1, m1_b, x00, x00p);
    inrf2_mfma<<<64 * 8, 256, 0, stream>>>(x00p, Bp2, x01, part2);
    finish2<<<64 * 24, 512, 0, stream>>>(x01, part2, m2_b, An);
    gemm3p<<<96, 512, 0, stream>>>(An, Bp3, part3);
    logitsk<<<64, 256, 0, stream>>>(part3, m3_b, fc_w, fc_b, logits);
}